// Round 3
// baseline (6068.052 us; speedup 1.0000x reference)
//
#include <hip/hip_runtime.h>
#include <hip/hip_bf16.h>

typedef __hip_bfloat16 bf16;
typedef unsigned short u16;
typedef unsigned int u32;

#define NS 200000
#define NEN 200000
#define NPL 20000
#define NT 1000
#define EE 200000
#define ETPE 20000
#define HID 64
#define HC 256
#define EDIM 6
#define OUTD 32

static __device__ __forceinline__ float b2f(bf16 x) { return __bfloat162float(x); }
static __device__ __forceinline__ bf16 f2b(float x) { return __float2bfloat16(x); }
static __device__ __forceinline__ u16 f2bu(float x) { bf16 b = __float2bfloat16(x); return *reinterpret_cast<u16*>(&b); }
static __device__ __forceinline__ float rl(float v, int l) {
    return __int_as_float(__builtin_amdgcn_readlane(__float_as_int(v), l));
}

__global__ __launch_bounds__(256) void k_fill_f(float* __restrict__ o, int n, float v)
{
    int i = blockIdx.x * 256 + threadIdx.x;
    if (i < n) o[i] = v;
}

__global__ __launch_bounds__(256) void k_cvt_f2b(const float* __restrict__ in, bf16* __restrict__ o, int n)
{
    int i = blockIdx.x * 256 + threadIdx.x;
    if (i < n) o[i] = f2b(in[i]);
}

// h[node,c] = x @ Wn + bn + emb_t[tidx] + emb_b[bidx]   (f32 in, bf16 out)
__global__ __launch_bounds__(256) void k_init_nodes(
    const float* __restrict__ x, const int* __restrict__ tidx, const int* __restrict__ bidx,
    const float* __restrict__ Wn, const float* __restrict__ bn,
    const float* __restrict__ embt, const float* __restrict__ embb,
    bf16* __restrict__ h, int N)
{
    int i = blockIdx.x * 256 + threadIdx.x;
    if (i >= N * HID) return;
    int node = i >> 6, c = i & 63;
    float acc = bn[c] + embt[tidx[node] * HID + c] + embb[bidx[node] * HID + c];
#pragma unroll
    for (int j = 0; j < 5; ++j)
        acc += x[node * 5 + j] * Wn[j * HID + c];
    h[i] = f2b(acc);
}

// Precompute A_h = Wq_h Wk_h^T, packed bf16x4 per (j,i): Apk[(lr*64+j)*64+i] = {h0|h1, h2|h3}
__global__ __launch_bounds__(256) void k_prep_A(
    const float* __restrict__ Wq, const float* __restrict__ Wk, uint2* __restrict__ Apk)
{
    __shared__ float sA[256];
    const int lr = blockIdx.x >> 6, j = blockIdx.x & 63;
    const int h = threadIdx.x >> 6, i = threadIdx.x & 63;
    const float* wqr = Wq + ((size_t)(lr * 64 + j)) * HC + h * 64;
    const float* wkr = Wk + ((size_t)(lr * 64 + i)) * HC + h * 64;
    float a = 0.f;
#pragma unroll 8
    for (int c = 0; c < 64; ++c) a += wqr[c] * wkr[c];
    sA[h * 64 + i] = a;
    __syncthreads();
    if (threadIdx.x < 64) {
        int ii = threadIdx.x;
        u32 x = (u32)f2bu(sA[ii]) | ((u32)f2bu(sA[64 + ii]) << 16);
        u32 y = (u32)f2bu(sA[128 + ii]) | ((u32)f2bu(sA[192 + ii]) << 16);
        Apk[((size_t)blockIdx.x << 6) + ii] = make_uint2(x, y);
    }
}

// Small tables: B=Wq We^T, u=Wq(bk+be), w=Wk^T bq, z=We^T bq, c0=bq.(bk+be); V/E repacks
__global__ __launch_bounds__(256) void k_prep_small(
    const float* __restrict__ Wq, const float* __restrict__ bq,
    const float* __restrict__ Wk, const float* __restrict__ bk,
    const float* __restrict__ Wv, const float* __restrict__ bv,
    const float* __restrict__ We, const float* __restrict__ be,
    float* __restrict__ Bpk, float* __restrict__ upk, float* __restrict__ wpk,
    float* __restrict__ zpk, float* __restrict__ c0pk,
    uint2* __restrict__ Wvpk, float* __restrict__ Wepk, float* __restrict__ bvepk)
{
    const int lr = blockIdx.x;
    const float* Wq_ = Wq + (size_t)lr * HID * HC;
    const float* Wk_ = Wk + (size_t)lr * HID * HC;
    const float* Wv_ = Wv + (size_t)lr * HID * HC;
    const float* We_ = We + (size_t)lr * EDIM * HC;
    const float* bq_ = bq + (size_t)lr * HC;
    const float* bk_ = bk + (size_t)lr * HC;
    const float* bv_ = bv + (size_t)lr * HC;
    const float* be_ = be + (size_t)lr * HC;

    for (int idx = threadIdx.x; idx < 64 * 6 * 4; idx += 256) {
        int h = idx & 3, t = (idx >> 2) % 6, j = idx / 24;
        float a = 0.f;
        for (int c = 0; c < 64; ++c)
            a += Wq_[j * HC + h * 64 + c] * We_[t * HC + h * 64 + c];
        Bpk[lr * 1536 + idx] = a;
    }
    {
        int idx = threadIdx.x, h = idx & 3, i = idx >> 2;
        float au = 0.f, aw = 0.f;
        for (int c = 0; c < 64; ++c) {
            int cc = h * 64 + c;
            au += Wq_[i * HC + cc] * (bk_[cc] + be_[cc]);
            aw += bq_[cc] * Wk_[i * HC + cc];
        }
        upk[lr * 256 + idx] = au;
        wpk[lr * 256 + idx] = aw;
    }
    if (threadIdx.x < 24) {
        int h = threadIdx.x & 3, t = threadIdx.x >> 2;
        float a = 0.f;
        for (int c = 0; c < 64; ++c) { int cc = h * 64 + c; a += bq_[cc] * We_[t * HC + cc]; }
        zpk[lr * 24 + threadIdx.x] = a;
    }
    if (threadIdx.x < 4) {
        int h = threadIdx.x;
        float a = 0.f;
        for (int c = 0; c < 64; ++c) { int cc = h * 64 + c; a += bq_[cc] * (bk_[cc] + be_[cc]); }
        c0pk[lr * 4 + h] = a;
    }
    for (int idx = threadIdx.x; idx < 4096; idx += 256) {
        int c = idx & 63, j = idx >> 6;
        uint2 a;
        a.x = (u32)f2bu(Wv_[j * HC + c]) | ((u32)f2bu(Wv_[j * HC + 64 + c]) << 16);
        a.y = (u32)f2bu(Wv_[j * HC + 128 + c]) | ((u32)f2bu(Wv_[j * HC + 192 + c]) << 16);
        Wvpk[lr * 4096 + idx] = a;
    }
    for (int idx = threadIdx.x; idx < 1536; idx += 256) {
        int h = idx & 3, c = (idx >> 2) & 63, t = idx >> 8;
        Wepk[lr * 1536 + idx] = We_[t * HC + h * 64 + c];
    }
    {
        int idx = threadIdx.x, h = idx & 3, c = idx >> 2;
        bvepk[lr * 256 + idx] = bv_[h * 64 + c] + be_[h * 64 + c];
    }
}

// g[N,64] += in[N,64] @ W[64,64] + b   (in bf16, W/bias f32)
__global__ __launch_bounds__(256) void k_skip64(
    const bf16* __restrict__ in, const float* __restrict__ W, const float* __restrict__ bias,
    float* __restrict__ g, int N)
{
    __shared__ float hs[4][64];
    const int c = threadIdx.x & 63;
    const int sub = threadIdx.x >> 6;
    float w[64];
#pragma unroll
    for (int j = 0; j < 64; ++j) w[j] = W[j * HID + c];
    const float bc = bias[c];
    const int ntiles = (N + 3) >> 2;
    for (int t = blockIdx.x; t < ntiles; t += gridDim.x) {
        const int i0 = t << 2;
        __syncthreads();
        {
            int r = threadIdx.x >> 6, col = threadIdx.x & 63;
            int row = i0 + r;
            hs[r][col] = (row < N) ? b2f(in[row * HID + col]) : 0.f;
        }
        __syncthreads();
        int row = i0 + sub;
        float a0 = 0.f, a1 = 0.f, a2 = 0.f, a3 = 0.f;
#pragma unroll
        for (int j = 0; j < 64; j += 4) {
            a0 += hs[sub][j + 0] * w[j + 0];
            a1 += hs[sub][j + 1] * w[j + 1];
            a2 += hs[sub][j + 2] * w[j + 2];
            a3 += hs[sub][j + 3] * w[j + 3];
        }
        if (row < N) g[row * HID + c] += bc + ((a0 + a1) + (a2 + a3));
    }
}

// Fused logits: logit_h = ( hd^T A_h hs + hd^T B_h ea + hd.u + w.hs + z.ea + c0 ) / 8
__global__ __launch_bounds__(256) void k_edge_logits_f(
    const int* __restrict__ src, const int* __restrict__ dst, const float* __restrict__ ea,
    const bf16* __restrict__ hsrc, const bf16* __restrict__ hdst,
    const uint2* __restrict__ Apk, const float* __restrict__ Bpk,
    const float* __restrict__ upk, const float* __restrict__ wpk,
    const float* __restrict__ zpk, const float* __restrict__ c0pk,
    float* __restrict__ logits, float* __restrict__ den, int nE)
{
    __shared__ uint2 As[4096];
    __shared__ float Bs[1536];
    __shared__ float us[256], wsh[256];
    __shared__ float zs[24], c0s[4];
    for (int idx = threadIdx.x; idx < 4096; idx += 256) As[idx] = Apk[idx];
    for (int idx = threadIdx.x; idx < 1536; idx += 256) Bs[idx] = Bpk[idx];
    us[threadIdx.x] = upk[threadIdx.x];
    wsh[threadIdx.x] = wpk[threadIdx.x];
    if (threadIdx.x < 24) zs[threadIdx.x] = zpk[threadIdx.x];
    if (threadIdx.x < 4) c0s[threadIdx.x] = c0pk[threadIdx.x];
    __syncthreads();
    const int lane = threadIdx.x & 63;
    const int wv = (blockIdx.x << 2) + (threadIdx.x >> 6);
    const int stride = gridDim.x << 2;
    for (int p = wv; (p << 1) < nE; p += stride) {
        const int e0 = p << 1, e1 = e0 + 1;
        const bool v1 = (e1 < nE);
        const int s0 = src[e0], d0 = dst[e0];
        const int s1 = v1 ? src[e1] : s0, d1 = v1 ? dst[e1] : d0;
        const float hd0 = b2f(hdst[(size_t)d0 * 64 + lane]);
        const float hs0 = b2f(hsrc[(size_t)s0 * 64 + lane]);
        const float hd1 = b2f(hdst[(size_t)d1 * 64 + lane]);
        const float hs1 = b2f(hsrc[(size_t)s1 * 64 + lane]);
        float ea0[6], ea1[6];
#pragma unroll
        for (int t = 0; t < 6; ++t) {
            ea0[t] = ea[(size_t)e0 * 6 + t];
            ea1[t] = v1 ? ea[(size_t)e1 * 6 + t] : 0.f;
        }
        float t0[4], t1[4], tA0[4] = {0, 0, 0, 0}, tA1[4] = {0, 0, 0, 0};
#pragma unroll
        for (int h = 0; h < 4; ++h) {
            float b0 = us[lane * 4 + h], b1 = us[lane * 4 + h];
#pragma unroll
            for (int t = 0; t < 6; ++t) {
                b0 += ea0[t] * Bs[(lane * 6 + t) * 4 + h];
                b1 += ea1[t] * Bs[(lane * 6 + t) * 4 + h];
            }
            t0[h] = hd0 * b0 + hs0 * wsh[lane * 4 + h];
            t1[h] = hd1 * b1 + hs1 * wsh[lane * 4 + h];
        }
        if (lane == 0) {
#pragma unroll
            for (int h = 0; h < 4; ++h) {
                float z0 = c0s[h], z1 = c0s[h];
#pragma unroll
                for (int t = 0; t < 6; ++t) { z0 += ea0[t] * zs[t * 4 + h]; z1 += ea1[t] * zs[t * 4 + h]; }
                t0[h] += z0; t1[h] += z1;
            }
        }
#pragma unroll
        for (int j = 0; j < 64; ++j) {
            uint2 a = As[(j << 6) + lane];
            float a0 = __int_as_float(a.x << 16), a1 = __int_as_float(a.x & 0xffff0000u);
            float a2 = __int_as_float(a.y << 16), a3 = __int_as_float(a.y & 0xffff0000u);
            float x0 = rl(hd0, j), x1 = rl(hd1, j);
            tA0[0] += x0 * a0; tA0[1] += x0 * a1; tA0[2] += x0 * a2; tA0[3] += x0 * a3;
            tA1[0] += x1 * a0; tA1[1] += x1 * a1; tA1[2] += x1 * a2; tA1[3] += x1 * a3;
        }
#pragma unroll
        for (int h = 0; h < 4; ++h) { t0[h] += tA0[h] * hs0; t1[h] += tA1[h] * hs1; }
#pragma unroll
        for (int m = 32; m >= 1; m >>= 1) {
#pragma unroll
            for (int h = 0; h < 4; ++h) {
                t0[h] += __shfl_xor(t0[h], m);
                t1[h] += __shfl_xor(t1[h], m);
            }
        }
        if (lane < 4) {
            float l = ((lane == 0) ? t0[0] : (lane == 1) ? t0[1] : (lane == 2) ? t0[2] : t0[3]) * 0.125f;
            logits[(size_t)e0 * 4 + lane] = l;
            atomicAdd(&den[(size_t)d0 * 4 + lane], __expf(l));
        } else if (lane < 8 && v1) {
            int h = lane - 4;
            float l = ((h == 0) ? t1[0] : (h == 1) ? t1[1] : (h == 2) ? t1[2] : t1[3]) * 0.125f;
            logits[(size_t)e1 * 4 + h] = l;
            atomicAdd(&den[(size_t)d1 * 4 + h], __expf(l));
        }
    }
}

// Fused accum: g[d,c] += sum_h alpha_h * ( (Wv^T hs)_{h,c} + (We^T ea)_{h,c} + bv+be ) / 4
__global__ __launch_bounds__(256) void k_edge_accum_f(
    const int* __restrict__ src, const int* __restrict__ dst, const float* __restrict__ ea,
    const bf16* __restrict__ hsrc,
    const uint2* __restrict__ Wvpk, const float* __restrict__ Wepk, const float* __restrict__ bvepk,
    const float* __restrict__ logits, const float* __restrict__ den,
    float* __restrict__ g, int nE)
{
    __shared__ uint2 Vs[4096];
    __shared__ float Es[1536];
    __shared__ float bs[256];
    for (int idx = threadIdx.x; idx < 4096; idx += 256) Vs[idx] = Wvpk[idx];
    for (int idx = threadIdx.x; idx < 1536; idx += 256) Es[idx] = Wepk[idx];
    bs[threadIdx.x] = bvepk[threadIdx.x];
    __syncthreads();
    const int lane = threadIdx.x & 63;
    const int wv = (blockIdx.x << 2) + (threadIdx.x >> 6);
    const int stride = gridDim.x << 2;
    for (int p = wv; (p << 1) < nE; p += stride) {
        const int e0 = p << 1, e1 = e0 + 1;
        const bool v1 = (e1 < nE);
        const int s0 = src[e0], d0 = dst[e0];
        const int s1 = v1 ? src[e1] : s0, d1 = v1 ? dst[e1] : d0;
        const float hs0 = b2f(hsrc[(size_t)s0 * 64 + lane]);
        const float hs1 = b2f(hsrc[(size_t)s1 * 64 + lane]);
        float ea0[6], ea1[6];
#pragma unroll
        for (int t = 0; t < 6; ++t) {
            ea0[t] = ea[(size_t)e0 * 6 + t];
            ea1[t] = v1 ? ea[(size_t)e1 * 6 + t] : 0.f;
        }
        float al0[4], al1[4];
#pragma unroll
        for (int h = 0; h < 4; ++h) {
            al0[h] = __expf(logits[(size_t)e0 * 4 + h]) / den[(size_t)d0 * 4 + h] * 0.25f;
            al1[h] = v1 ? __expf(logits[(size_t)e1 * 4 + h]) / den[(size_t)d1 * 4 + h] * 0.25f : 0.f;
        }
        float t0[4], t1[4];
#pragma unroll
        for (int h = 0; h < 4; ++h) {
            float x0 = bs[lane * 4 + h], x1 = bs[lane * 4 + h];
#pragma unroll
            for (int t = 0; t < 6; ++t) {
                x0 += ea0[t] * Es[(t * 64 + lane) * 4 + h];
                x1 += ea1[t] * Es[(t * 64 + lane) * 4 + h];
            }
            t0[h] = x0; t1[h] = x1;
        }
#pragma unroll
        for (int j = 0; j < 64; ++j) {
            uint2 a = Vs[(j << 6) + lane];
            float a0 = __int_as_float(a.x << 16), a1 = __int_as_float(a.x & 0xffff0000u);
            float a2 = __int_as_float(a.y << 16), a3 = __int_as_float(a.y & 0xffff0000u);
            float x0 = rl(hs0, j), x1 = rl(hs1, j);
            t0[0] += x0 * a0; t0[1] += x0 * a1; t0[2] += x0 * a2; t0[3] += x0 * a3;
            t1[0] += x1 * a0; t1[1] += x1 * a1; t1[2] += x1 * a2; t1[3] += x1 * a3;
        }
        float o0 = al0[0] * t0[0] + al0[1] * t0[1] + al0[2] * t0[2] + al0[3] * t0[3];
        atomicAdd(&g[(size_t)d0 * 64 + lane], o0);
        if (v1) {
            float o1 = al1[0] * t1[0] + al1[1] * t1[1] + al1[2] * t1[2] + al1[3] * t1[3];
            atomicAdd(&g[(size_t)d1 * 64 + lane], o1);
        }
    }
}

__global__ __launch_bounds__(256) void k_relu_g2h(const float* __restrict__ g, bf16* __restrict__ h, int n)
{
    int i = blockIdx.x * 256 + threadIdx.x;
    if (i < n) h[i] = f2b(fmaxf(g[i], 0.f));
}

__global__ __launch_bounds__(256) void k_relu_bf(bf16* __restrict__ h, int n)
{
    int i = blockIdx.x * 256 + threadIdx.x;
    if (i < n) { float x = b2f(h[i]); h[i] = f2b(x > 0.f ? x : 0.f); }
}

// out[N,32] = h1[N,64] @ W[64,32] + b   (h bf16, W/bias/out f32)
__global__ __launch_bounds__(256) void k_head(
    const bf16* __restrict__ h1, const float* __restrict__ W, const float* __restrict__ bias,
    float* __restrict__ out, int N)
{
    __shared__ float Ws[HID * OUTD];
    __shared__ float hs[8][HID];
    for (int idx = threadIdx.x; idx < HID * OUTD; idx += 256) Ws[idx] = W[idx];
    const int o = threadIdx.x & 31;
    const int sub = threadIdx.x >> 5;
    const float bo = bias[o];
    const int ntiles = (N + 7) >> 3;
    for (int t = blockIdx.x; t < ntiles; t += gridDim.x) {
        const int i0 = t << 3;
        __syncthreads();
#pragma unroll
        for (int e = 0; e < 2; ++e) {
            int idx = e * 256 + threadIdx.x;
            int r = idx >> 6, col = idx & 63;
            int row = i0 + r;
            hs[r][col] = (row < N) ? b2f(h1[row * HID + col]) : 0.f;
        }
        __syncthreads();
        int row = i0 + sub;
        float a0 = 0.f, a1 = 0.f;
#pragma unroll
        for (int j = 0; j < HID; j += 2) {
            a0 += hs[sub][j] * Ws[j * OUTD + o];
            a1 += hs[sub][j + 1] * Ws[(j + 1) * OUTD + o];
        }
        if (row < N) out[row * OUTD + o] = bo + a0 + a1;
    }
}

extern "C" void kernel_launch(void* const* d_in, const int* in_sizes, int n_in,
                              void* d_out, int out_size, void* d_ws, size_t ws_size,
                              hipStream_t stream)
{
    const float* x_start = (const float*)d_in[0];
    const float* x_end   = (const float*)d_in[1];
    const int* start_type_idx = (const int*)d_in[2];
    const int* start_body_idx = (const int*)d_in[3];
    const int* end_type_idx   = (const int*)d_in[4];
    const int* end_body_idx   = (const int*)d_in[5];
    const int* src_ps = (const int*)d_in[6];
    const int* dst_ps = (const int*)d_in[7];
    const int* src_se = (const int*)d_in[8];
    const int* dst_se = (const int*)d_in[9];
    const int* src_es = (const int*)d_in[10];
    const int* dst_es = (const int*)d_in[11];
    const int* src_tp = (const int*)d_in[12];
    const int* dst_tp = (const int*)d_in[13];
    const float* ea_ps = (const float*)d_in[14];
    const float* ea_se = (const float*)d_in[15];
    const float* ea_es = (const float*)d_in[16];
    const float* ea_tp = (const float*)d_in[17];
    const float* emb_start_type = (const float*)d_in[18];
    const float* emb_start_body = (const float*)d_in[19];
    const float* emb_end_type   = (const float*)d_in[20];
    const float* emb_end_body   = (const float*)d_in[21];
    const float* emb_player = (const float*)d_in[22];
    const float* emb_team   = (const float*)d_in[23];
    const float* W_start = (const float*)d_in[24];
    const float* b_start = (const float*)d_in[25];
    const float* W_end   = (const float*)d_in[26];
    const float* b_end   = (const float*)d_in[27];
    const float* Wq = (const float*)d_in[28];
    const float* bq = (const float*)d_in[29];
    const float* Wk = (const float*)d_in[30];
    const float* bk = (const float*)d_in[31];
    const float* Wv = (const float*)d_in[32];
    const float* bv = (const float*)d_in[33];
    const float* We = (const float*)d_in[34];
    const float* be = (const float*)d_in[35];
    const float* Wskip = (const float*)d_in[36];
    const float* bskip = (const float*)d_in[37];
    const float* W_head = (const float*)d_in[38];
    const float* b_head = (const float*)d_in[39];

    // ---- workspace carve (~168.5 MB, proven to fit in round 2) ----
    size_t off = 0;
    char* base = (char*)d_ws;
    auto carve = [&](size_t bytes) -> char* { char* q = base + off; off += bytes; return q; };
    bf16* h0 = (bf16*)carve((size_t)NS * HID * 2);
    bf16* h1 = (bf16*)carve((size_t)NEN * HID * 2);
    bf16* h2 = (bf16*)carve((size_t)NPL * HID * 2);
    bf16* h3 = (bf16*)carve((size_t)NT * HID * 2);
    float* g0 = (float*)carve((size_t)NS * HID * 4);
    float* g1 = (float*)carve((size_t)NEN * HID * 4);
    float* g2 = (float*)carve((size_t)NPL * HID * 4);
    uint2* Apk = (uint2*)carve(8 * 4096 * 8);
    float* Bpk = (float*)carve(8 * 1536 * 4);
    float* upk = (float*)carve(8 * 256 * 4);
    float* wpk = (float*)carve(8 * 256 * 4);
    float* zpk = (float*)carve(8 * 24 * 4);
    float* c0pk = (float*)carve(8 * 4 * 4);
    uint2* Wvpk = (uint2*)carve(8 * 4096 * 8);
    float* Wepk = (float*)carve(8 * 1536 * 4);
    float* bvepk = (float*)carve(8 * 256 * 4);
    float* logits = (float*)carve((size_t)EE * 4 * 4);
    float* den = (float*)carve((size_t)200000 * 4 * 4);
    const size_t req = off;

    if (ws_size < req) {
        // diagnostic: encode ws_size (in MB) into the output so absmax reveals it
        k_fill_f<<<(out_size + 255) / 256, 256, 0, stream>>>((float*)d_out, out_size, (float)(ws_size >> 20));
        return;
    }

    // precompute folded attention tables
    k_prep_A<<<512, 256, 0, stream>>>(Wq, Wk, Apk);
    k_prep_small<<<8, 256, 0, stream>>>(Wq, bq, Wk, bk, Wv, bv, We, be,
                                        Bpk, upk, wpk, zpk, c0pk, Wvpk, Wepk, bvepk);

    // initial node features
    k_init_nodes<<<(NS * HID + 255) / 256, 256, 0, stream>>>(
        x_start, start_type_idx, start_body_idx, W_start, b_start,
        emb_start_type, emb_start_body, h0, NS);
    k_init_nodes<<<(NEN * HID + 255) / 256, 256, 0, stream>>>(
        x_end, end_type_idx, end_body_idx, W_end, b_end,
        emb_end_type, emb_end_body, h1, NEN);
    k_cvt_f2b<<<(NPL * HID + 255) / 256, 256, 0, stream>>>(emb_player, h2, NPL * HID);
    k_cvt_f2b<<<(NT * HID + 255) / 256, 256, 0, stream>>>(emb_team, h3, NT * HID);

    struct RelDesc {
        int srcN, dstN, nE;
        const int *src, *dst;
        const float* ea;
        bf16 *hsrc, *hdst;
        float* gdst;
    };

    for (int l = 0; l < 2; ++l) {
        hipMemsetAsync(g0, 0, (size_t)NS * HID * 4, stream);
        hipMemsetAsync(g1, 0, (size_t)NEN * HID * 4, stream);
        hipMemsetAsync(g2, 0, (size_t)NPL * HID * 4, stream);

        RelDesc rels[4] = {
            { NPL, NS,  EE,   src_ps, dst_ps, ea_ps, h2, h0, g0 },
            { NS,  NEN, EE,   src_se, dst_se, ea_se, h0, h1, g1 },
            { NEN, NS,  EE,   src_es, dst_es, ea_es, h1, h0, g0 },
            { NT,  NPL, ETPE, src_tp, dst_tp, ea_tp, h3, h2, g2 },
        };

        for (int r = 0; r < 4; ++r) {
            const RelDesc& R = rels[r];
            const int wi = l * 4 + r;
            const float* Ws_ = Wskip + (size_t)wi * HID * HID;
            const float* bs_ = bskip + (size_t)wi * HID;

            int gsk = (R.dstN + 3) / 4; if (gsk > 2048) gsk = 2048;
            int gE = (R.nE + 7) / 8; if (gE > 768) gE = 768;

            k_skip64<<<gsk, 256, 0, stream>>>(R.hdst, Ws_, bs_, R.gdst, R.dstN);
            hipMemsetAsync(den, 0, (size_t)R.dstN * 4 * 4, stream);
            k_edge_logits_f<<<gE, 256, 0, stream>>>(
                R.src, R.dst, R.ea, R.hsrc, R.hdst,
                Apk + (size_t)wi * 4096, Bpk + (size_t)wi * 1536,
                upk + (size_t)wi * 256, wpk + (size_t)wi * 256,
                zpk + (size_t)wi * 24, c0pk + (size_t)wi * 4,
                logits, den, R.nE);
            k_edge_accum_f<<<gE, 256, 0, stream>>>(
                R.src, R.dst, R.ea, R.hsrc,
                Wvpk + (size_t)wi * 4096, Wepk + (size_t)wi * 1536, bvepk + (size_t)wi * 256,
                logits, den, R.gdst, R.nE);
        }

        k_relu_g2h<<<(NS * HID + 255) / 256, 256, 0, stream>>>(g0, h0, NS * HID);
        k_relu_g2h<<<(NEN * HID + 255) / 256, 256, 0, stream>>>(g1, h1, NEN * HID);
        k_relu_g2h<<<(NPL * HID + 255) / 256, 256, 0, stream>>>(g2, h2, NPL * HID);
        k_relu_bf<<<(NT * HID + 255) / 256, 256, 0, stream>>>(h3, NT * HID);
    }

    k_head<<<2048, 256, 0, stream>>>(h1, W_head, b_head, (float*)d_out, NEN);
}

// Round 5
// 1917.448 us; speedup vs baseline: 3.1647x; 3.1647x over previous
//
#include <hip/hip_runtime.h>
#include <hip/hip_bf16.h>

typedef __hip_bfloat16 bf16;
typedef unsigned int u32;
typedef __attribute__((ext_vector_type(8))) short short8;
typedef __attribute__((ext_vector_type(4))) float float4v;

#define NS 200000
#define NEN 200000
#define NPL 20000
#define NT 1000
#define EE 200000
#define ETPE 20000
#define HID 64
#define HC 256
#define EDIM 6
#define OUTD 32
#define CH 100000   // Q/V chunk rows (keeps QV buffer at 57.6 MB; ws_size is 256 MB)

static __device__ __forceinline__ float b2f(bf16 x) { return __bfloat162float(x); }
static __device__ __forceinline__ bf16 f2b(float x) { return __float2bfloat16(x); }

__global__ __launch_bounds__(256) void k_fill_f(float* __restrict__ o, int n, float v)
{
    int i = blockIdx.x * 256 + threadIdx.x;
    if (i < n) o[i] = v;
}

__global__ __launch_bounds__(256) void k_cvt_f2b(const float* __restrict__ in, bf16* __restrict__ o, int n)
{
    int i = blockIdx.x * 256 + threadIdx.x;
    if (i < n) o[i] = f2b(in[i]);
}

__global__ __launch_bounds__(256) void k_init_nodes(
    const float* __restrict__ x, const int* __restrict__ tidx, const int* __restrict__ bidx,
    const float* __restrict__ Wn, const float* __restrict__ bn,
    const float* __restrict__ embt, const float* __restrict__ embb,
    bf16* __restrict__ h, int N)
{
    int i = blockIdx.x * 256 + threadIdx.x;
    if (i >= N * HID) return;
    int node = i >> 6, c = i & 63;
    float acc = bn[c] + embt[tidx[node] * HID + c] + embb[bidx[node] * HID + c];
#pragma unroll
    for (int j = 0; j < 5; ++j)
        acc += x[node * 5 + j] * Wn[j * HID + c];
    h[i] = f2b(acc);
}

// Build folded Q-weight [64][288] f32 and bias [288] per (lr):
//   cols h*64+i   : A_h[j][i] = sum_c Wq[j,hc]*Wk[i,hc]    bias: sum_c bq[hc]*Wk[i,hc]
//   cols 256+h*6+t: sum_c Wq[j,hc]*We[t,hc]                bias: sum_c bq[hc]*We[t,hc]
//   col 280+h     : sum_c Wq[j,hc]*(bk+be)[hc]             bias: sum_c bq[hc]*(bk+be)[hc]
__global__ __launch_bounds__(256) void k_prep_q(
    const float* __restrict__ Wq, const float* __restrict__ bq,
    const float* __restrict__ Wk, const float* __restrict__ bk,
    const float* __restrict__ We, const float* __restrict__ be,
    float* __restrict__ WQeff, float* __restrict__ QBias)
{
    const int lr = blockIdx.x >> 2, h = blockIdx.x & 3;
    __shared__ float Ql[65 * 64];
    __shared__ float Rl[71 * 64];
    const float* Wq_ = Wq + (size_t)lr * HID * HC;
    const float* Wk_ = Wk + (size_t)lr * HID * HC;
    const float* We_ = We + (size_t)lr * EDIM * HC;
    const float* bq_ = bq + (size_t)lr * HC;
    const float* bk_ = bk + (size_t)lr * HC;
    const float* be_ = be + (size_t)lr * HC;
    for (int i = threadIdx.x; i < 65 * 64; i += 256) {
        int j = i >> 6, c = i & 63;
        Ql[i] = (j < 64) ? Wq_[j * HC + h * 64 + c] : bq_[h * 64 + c];
    }
    for (int i = threadIdx.x; i < 71 * 64; i += 256) {
        int r = i >> 6, c = i & 63;
        Rl[i] = (r < 64) ? Wk_[r * HC + h * 64 + c]
              : (r < 70) ? We_[(r - 64) * HC + h * 64 + c]
                         : (bk_[h * 64 + c] + be_[h * 64 + c]);
    }
    __syncthreads();
    for (int idx = threadIdx.x; idx < 65 * 71; idx += 256) {
        int j = idx / 71, col = idx % 71;
        float dot = 0.f;
#pragma unroll 8
        for (int c = 0; c < 64; ++c) dot += Ql[j * 64 + c] * Rl[col * 64 + c];
        int cm = (col < 64) ? (h * 64 + col) : (col < 70) ? (256 + h * 6 + (col - 64)) : (280 + h);
        if (j < 64) WQeff[((size_t)lr * 64 + j) * 288 + cm] = dot;
        else        QBias[(size_t)lr * 288 + cm] = dot;
    }
    for (int idx = threadIdx.x; idx < 64 * 4; idx += 256) {
        int j = idx >> 2, u = idx & 3;
        WQeff[((size_t)lr * 64 + j) * 288 + 284 + u] = 0.f;
    }
    if (threadIdx.x < 4) QBias[(size_t)lr * 288 + 284 + threadIdx.x] = 0.f;
}

__global__ __launch_bounds__(256) void k_prep_vbias(
    const float* __restrict__ bv, const float* __restrict__ be, float* __restrict__ bveff)
{
    int i = blockIdx.x * 256 + threadIdx.x;   // 8 * 256
    bveff[i] = bv[i] + be[i];
}

// Pack f32 row-major [64][ld] -> bf16 MFMA B-frag:
// frag[((tile*2+ks)*64 + lane)*8 + j] = W[ks*32 + (lane>>4)*8 + j][tile*16 + (lane&15)]
__global__ __launch_bounds__(256) void k_pack(
    const float* __restrict__ src, bf16* __restrict__ dst,
    int ld, int matStride, int fragStride)
{
    const int mat = blockIdx.y, tile = blockIdx.x;
    const float* S = src + (size_t)mat * matStride;
    bf16* D = dst + (size_t)mat * fragStride + tile * 1024;
    for (int idx = threadIdx.x; idx < 1024; idx += 256) {
        int ks = idx >> 9, r = idx & 511;
        int lane = r >> 3, j = r & 7;
        int k = ks * 32 + ((lane >> 4) << 3) + j;
        int n = tile * 16 + (lane & 15);
        D[ks * 512 + r] = f2b(S[k * ld + n]);
    }
}

// Unified MFMA GEMM: out[N, NTILES*16] = h[N,64] @ Wfrag + bias
// MODE 0: bf16 '='; 1: f32 '='; 2: f32 '+='
template<int NTILES, int MODE>
__global__ __launch_bounds__(256, 3) void k_gemm(
    const bf16* __restrict__ hin, const bf16* __restrict__ wfrag,
    const float* __restrict__ bias, void* __restrict__ outp, int N)
{
    __shared__ __align__(16) short wl[NTILES * 1024];
    __shared__ __align__(16) short hl[64 * 72];
    __shared__ float bl[NTILES * 16];
    {
        const uint4* wsrc = (const uint4*)wfrag;
        uint4* wdst = (uint4*)wl;
        for (int i = threadIdx.x; i < NTILES * 128; i += 256) wdst[i] = wsrc[i];
        for (int i = threadIdx.x; i < NTILES * 16; i += 256) bl[i] = bias[i];
    }
    const int lane = threadIdx.x & 63, wv = threadIdx.x >> 6;
    const int m = lane & 15, q = lane >> 4;
    const int ntile_tot = (N + 63) >> 6;
    const int ldo = NTILES * 16;
    for (int t = blockIdx.x; t < ntile_tot; t += gridDim.x) {
        const int row0 = t << 6;
        __syncthreads();
        {
            const uint4* hsrc = (const uint4*)(hin + (size_t)row0 * 64);
            for (int i = threadIdx.x; i < 512; i += 256) {
                int r = i >> 3, cc = i & 7;
                uint4 v = (row0 + r < N) ? hsrc[i] : make_uint4(0u, 0u, 0u, 0u);
                *(uint4*)&hl[r * 72 + cc * 8] = v;
            }
        }
        __syncthreads();
        short8 a0 = *(const short8*)&hl[(wv * 16 + m) * 72 + q * 8];
        short8 a1 = *(const short8*)&hl[(wv * 16 + m) * 72 + 32 + q * 8];
        for (int nt = 0; nt < NTILES; ++nt) {
            short8 b0 = *(const short8*)&wl[(nt * 2 + 0) * 512 + lane * 8];
            short8 b1 = *(const short8*)&wl[(nt * 2 + 1) * 512 + lane * 8];
            float4v acc = {0.f, 0.f, 0.f, 0.f};
            acc = __builtin_amdgcn_mfma_f32_16x16x32_bf16(a0, b0, acc, 0, 0, 0);
            acc = __builtin_amdgcn_mfma_f32_16x16x32_bf16(a1, b1, acc, 0, 0, 0);
            const float bb = bl[nt * 16 + m];
            const int colg = nt * 16 + m;
#pragma unroll
            for (int r = 0; r < 4; ++r) {
                int row = row0 + wv * 16 + q * 4 + r;
                if (row < N) {
                    float val = acc[r] + bb;
                    if (MODE == 0)      ((bf16*)outp)[(size_t)row * ldo + colg] = f2b(val);
                    else if (MODE == 1) ((float*)outp)[(size_t)row * ldo + colg] = val;
                    else                ((float*)outp)[(size_t)row * ldo + colg] += val;
                }
            }
        }
    }
}

// logits (dst range [lo,hi)): logit_h = Q1_h[d].hs[s] + Q2_h[d].ea + Q3_h[d], /8
__global__ __launch_bounds__(256, 4) void k_elog(
    const int* __restrict__ src, const int* __restrict__ dst, const float* __restrict__ ea,
    const bf16* __restrict__ hsrc, const bf16* __restrict__ Q,
    float* __restrict__ logits, float* __restrict__ den, int nE, int lo, int hi)
{
    const int lane = threadIdx.x & 63;
    const int step = gridDim.x << 2;
    for (int e = (blockIdx.x << 2) + (threadIdx.x >> 6); e < nE; e += step) {
        const int d = dst[e];
        if (d < lo || d >= hi) continue;
        const int s = src[e];
        const bf16* qr = Q + (size_t)(d - lo) * 288;
        const float x = b2f(hsrc[(size_t)s * 64 + lane]);
        float p0 = b2f(qr[lane]) * x;
        float p1 = b2f(qr[64 + lane]) * x;
        float p2 = b2f(qr[128 + lane]) * x;
        float p3 = b2f(qr[192 + lane]) * x;
#pragma unroll
        for (int mm = 32; mm >= 1; mm >>= 1) {
            p0 += __shfl_xor(p0, mm);
            p1 += __shfl_xor(p1, mm);
            p2 += __shfl_xor(p2, mm);
            p3 += __shfl_xor(p3, mm);
        }
        if (lane < 4) {
            float l = (lane == 0) ? p0 : (lane == 1) ? p1 : (lane == 2) ? p2 : p3;
            float acc = b2f(qr[280 + lane]);
#pragma unroll
            for (int t = 0; t < 6; ++t)
                acc += b2f(qr[256 + lane * 6 + t]) * ea[(size_t)e * 6 + t];
            l = (l + acc) * 0.125f;
            logits[(size_t)e * 4 + lane] = l;
            atomicAdd(&den[(size_t)d * 4 + lane], __expf(l));
        }
    }
}

// accum (src range [lo,hi)): g[d,c] += sum_h alpha_h*(V[s]_{h,c} + (We^T ea)_{h,c})/4
__global__ __launch_bounds__(256, 4) void k_eacc(
    const int* __restrict__ src, const int* __restrict__ dst, const float* __restrict__ ea,
    const bf16* __restrict__ V, const float* __restrict__ Wer,
    const float* __restrict__ logits, const float* __restrict__ den,
    float* __restrict__ g, int nE, int lo, int hi)
{
    __shared__ float Wes[EDIM * HC];
    for (int i = threadIdx.x; i < EDIM * HC; i += 256) Wes[i] = Wer[i];
    __syncthreads();
    const int lane = threadIdx.x & 63;
    const int step = gridDim.x << 2;
    for (int e = (blockIdx.x << 2) + (threadIdx.x >> 6); e < nE; e += step) {
        const int s = src[e];
        if (s < lo || s >= hi) continue;
        const int d = dst[e];
        float ev[EDIM];
#pragma unroll
        for (int t = 0; t < EDIM; ++t) ev[t] = ea[(size_t)e * 6 + t];
        float al[4];
#pragma unroll
        for (int h = 0; h < 4; ++h)
            al[h] = __expf(logits[(size_t)e * 4 + h]) / den[(size_t)d * 4 + h] * 0.25f;
        float acc = 0.f;
#pragma unroll
        for (int h = 0; h < 4; ++h) {
            float val = b2f(V[(size_t)(s - lo) * 256 + h * 64 + lane]);
#pragma unroll
            for (int t = 0; t < EDIM; ++t) val += ev[t] * Wes[t * HC + h * 64 + lane];
            acc += al[h] * val;
        }
        atomicAdd(&g[(size_t)d * 64 + lane], acc);
    }
}

__global__ __launch_bounds__(256) void k_relu_g2h(const float* __restrict__ g, bf16* __restrict__ h, int n)
{
    int i = blockIdx.x * 256 + threadIdx.x;
    if (i < n) h[i] = f2b(fmaxf(g[i], 0.f));
}

__global__ __launch_bounds__(256) void k_relu_bf(bf16* __restrict__ h, int n)
{
    int i = blockIdx.x * 256 + threadIdx.x;
    if (i < n) { float x = b2f(h[i]); h[i] = f2b(x > 0.f ? x : 0.f); }
}

extern "C" void kernel_launch(void* const* d_in, const int* in_sizes, int n_in,
                              void* d_out, int out_size, void* d_ws, size_t ws_size,
                              hipStream_t stream)
{
    const float* x_start = (const float*)d_in[0];
    const float* x_end   = (const float*)d_in[1];
    const int* start_type_idx = (const int*)d_in[2];
    const int* start_body_idx = (const int*)d_in[3];
    const int* end_type_idx   = (const int*)d_in[4];
    const int* end_body_idx   = (const int*)d_in[5];
    const int* src_ps = (const int*)d_in[6];
    const int* dst_ps = (const int*)d_in[7];
    const int* src_se = (const int*)d_in[8];
    const int* dst_se = (const int*)d_in[9];
    const int* src_es = (const int*)d_in[10];
    const int* dst_es = (const int*)d_in[11];
    const int* src_tp = (const int*)d_in[12];
    const int* dst_tp = (const int*)d_in[13];
    const float* ea_ps = (const float*)d_in[14];
    const float* ea_se = (const float*)d_in[15];
    const float* ea_es = (const float*)d_in[16];
    const float* ea_tp = (const float*)d_in[17];
    const float* emb_start_type = (const float*)d_in[18];
    const float* emb_start_body = (const float*)d_in[19];
    const float* emb_end_type   = (const float*)d_in[20];
    const float* emb_end_body   = (const float*)d_in[21];
    const float* emb_player = (const float*)d_in[22];
    const float* emb_team   = (const float*)d_in[23];
    const float* W_start = (const float*)d_in[24];
    const float* b_start = (const float*)d_in[25];
    const float* W_end   = (const float*)d_in[26];
    const float* b_end   = (const float*)d_in[27];
    const float* Wq = (const float*)d_in[28];
    const float* bq = (const float*)d_in[29];
    const float* Wk = (const float*)d_in[30];
    const float* bk = (const float*)d_in[31];
    const float* Wv = (const float*)d_in[32];
    const float* bv = (const float*)d_in[33];
    const float* We = (const float*)d_in[34];
    const float* be = (const float*)d_in[35];
    const float* Wskip = (const float*)d_in[36];
    const float* bskip = (const float*)d_in[37];
    const float* W_head = (const float*)d_in[38];
    const float* b_head = (const float*)d_in[39];

    // ---- workspace carve (~226.6 MB; ws_size measured = 256 MB) ----
    size_t off = 0;
    char* base = (char*)d_ws;
    auto carve = [&](size_t bytes) -> char* {
        char* q = base + off; off += (bytes + 255) & ~(size_t)255; return q;
    };
    bf16* h0 = (bf16*)carve((size_t)NS * HID * 2);
    bf16* h1 = (bf16*)carve((size_t)NEN * HID * 2);
    bf16* h2 = (bf16*)carve((size_t)NPL * HID * 2);
    bf16* h3 = (bf16*)carve((size_t)NT * HID * 2);
    float* g0 = (float*)carve((size_t)NS * HID * 4);
    float* g1 = (float*)carve((size_t)NEN * HID * 4);
    float* g2 = (float*)carve((size_t)NPL * HID * 4);
    bf16* QV  = (bf16*)carve((size_t)CH * 288 * 2);       // Q chunk (288) / V chunk (256)
    float* logits = (float*)carve((size_t)EE * 4 * 4);
    float* den = (float*)carve((size_t)200000 * 4 * 4);
    float* WQeff = (float*)carve((size_t)8 * 64 * 288 * 4);
    float* QBias = (float*)carve((size_t)8 * 288 * 4);
    float* bveff = (float*)carve((size_t)8 * 256 * 4);
    bf16* Qfrag = (bf16*)carve((size_t)8 * 18 * 1024 * 2);
    bf16* Vfrag = (bf16*)carve((size_t)8 * 16 * 1024 * 2);
    bf16* SKfrag = (bf16*)carve((size_t)8 * 4 * 1024 * 2);
    bf16* HDfrag = (bf16*)carve((size_t)2 * 1024 * 2);
    const size_t req = off;

    if (ws_size < req) {
        k_fill_f<<<(out_size + 255) / 256, 256, 0, stream>>>((float*)d_out, out_size, (float)(ws_size >> 20));
        return;
    }

    // ---- weight prep + frag packing ----
    k_prep_q<<<32, 256, 0, stream>>>(Wq, bq, Wk, bk, We, be, WQeff, QBias);
    k_prep_vbias<<<8, 256, 0, stream>>>(bv, be, bveff);
    k_pack<<<dim3(18, 8), 256, 0, stream>>>(WQeff, Qfrag, 288, 64 * 288, 18 * 1024);
    k_pack<<<dim3(16, 8), 256, 0, stream>>>(Wv, Vfrag, 256, HID * HC, 16 * 1024);
    k_pack<<<dim3(4, 8), 256, 0, stream>>>(Wskip, SKfrag, 64, HID * HID, 4 * 1024);
    k_pack<<<dim3(2, 1), 256, 0, stream>>>(W_head, HDfrag, 32, 0, 2 * 1024);

    // ---- initial node features ----
    k_init_nodes<<<(NS * HID + 255) / 256, 256, 0, stream>>>(
        x_start, start_type_idx, start_body_idx, W_start, b_start,
        emb_start_type, emb_start_body, h0, NS);
    k_init_nodes<<<(NEN * HID + 255) / 256, 256, 0, stream>>>(
        x_end, end_type_idx, end_body_idx, W_end, b_end,
        emb_end_type, emb_end_body, h1, NEN);
    k_cvt_f2b<<<(NPL * HID + 255) / 256, 256, 0, stream>>>(emb_player, h2, NPL * HID);
    k_cvt_f2b<<<(NT * HID + 255) / 256, 256, 0, stream>>>(emb_team, h3, NT * HID);

    struct RelDesc {
        int srcN, dstN, nE;
        const int *src, *dst;
        const float* ea;
        bf16 *hsrc, *hdst;
        float* gdst;
    };

    auto gemmGrid = [](int N) { int g = (N + 63) / 64; return g > 2048 ? 2048 : g; };

    for (int l = 0; l < 2; ++l) {
        RelDesc rels[4] = {
            { NPL, NS,  EE,   src_ps, dst_ps, ea_ps, h2, h0, g0 },
            { NS,  NEN, EE,   src_se, dst_se, ea_se, h0, h1, g1 },
            { NEN, NS,  EE,   src_es, dst_es, ea_es, h1, h0, g0 },
            { NT,  NPL, ETPE, src_tp, dst_tp, ea_tp, h3, h2, g2 },
        };
        for (int r = 0; r < 4; ++r) {
            const RelDesc& R = rels[r];
            const int wi = l * 4 + r;
            int gE = (R.nE + 3) / 4; if (gE > 2048) gE = 2048;

            // skip term: '=' initializes g (first writer per dst type), '+=' for second
            if (r == 2)
                k_gemm<4, 2><<<gemmGrid(R.dstN), 256, 0, stream>>>(
                    R.hdst, SKfrag + (size_t)wi * 4096, bskip + (size_t)wi * HID, R.gdst, R.dstN);
            else
                k_gemm<4, 1><<<gemmGrid(R.dstN), 256, 0, stream>>>(
                    R.hdst, SKfrag + (size_t)wi * 4096, bskip + (size_t)wi * HID, R.gdst, R.dstN);

            hipMemsetAsync(den, 0, (size_t)R.dstN * 4 * 4, stream);
            for (int c0 = 0; c0 < R.dstN; c0 += CH) {
                int cnt = (R.dstN - c0 < CH) ? (R.dstN - c0) : CH;
                k_gemm<18, 0><<<gemmGrid(cnt), 256, 0, stream>>>(
                    R.hdst + (size_t)c0 * 64, Qfrag + (size_t)wi * 18432,
                    QBias + (size_t)wi * 288, QV, cnt);
                k_elog<<<gE, 256, 0, stream>>>(R.src, R.dst, R.ea, R.hsrc, QV,
                                               logits, den, R.nE, c0, c0 + cnt);
            }
            for (int c0 = 0; c0 < R.srcN; c0 += CH) {
                int cnt = (R.srcN - c0 < CH) ? (R.srcN - c0) : CH;
                k_gemm<16, 0><<<gemmGrid(cnt), 256, 0, stream>>>(
                    R.hsrc + (size_t)c0 * 64, Vfrag + (size_t)wi * 16384,
                    bveff + (size_t)wi * 256, QV, cnt);
                k_eacc<<<gE, 256, 0, stream>>>(R.src, R.dst, R.ea, QV,
                                               We + (size_t)wi * EDIM * HC,
                                               logits, den, R.gdst, R.nE, c0, c0 + cnt);
            }
        }
        k_relu_g2h<<<(NS * HID + 255) / 256, 256, 0, stream>>>(g0, h0, NS * HID);
        k_relu_g2h<<<(NEN * HID + 255) / 256, 256, 0, stream>>>(g1, h1, NEN * HID);
        k_relu_g2h<<<(NPL * HID + 255) / 256, 256, 0, stream>>>(g2, h2, NPL * HID);
        k_relu_bf<<<(NT * HID + 255) / 256, 256, 0, stream>>>(h3, NT * HID);
    }

    k_gemm<2, 1><<<2048, 256, 0, stream>>>(h1, HDfrag, b_head, d_out, NEN);
}

// Round 6
// 1788.860 us; speedup vs baseline: 3.3921x; 1.0719x over previous
//
#include <hip/hip_runtime.h>
#include <hip/hip_bf16.h>

typedef __hip_bfloat16 bf16;
typedef unsigned int u32;
typedef __attribute__((ext_vector_type(8))) short short8;
typedef __attribute__((ext_vector_type(4))) float float4v;

#define NS 200000
#define NEN 200000
#define NPL 20000
#define NT 1000
#define EE 200000
#define ETPE 20000
#define HID 64
#define HC 256
#define EDIM 6
#define OUTD 32
#define CH 100000   // Q/V chunk rows; ws_size measured = 256 MB

static __device__ __forceinline__ float b2f(bf16 x) { return __bfloat162float(x); }
static __device__ __forceinline__ bf16 f2b(float x) { return __float2bfloat16(x); }
static __device__ __forceinline__ float blo(u32 u) { return __int_as_float(u << 16); }
static __device__ __forceinline__ float bhi(u32 u) { return __int_as_float(u & 0xffff0000u); }

__global__ __launch_bounds__(256) void k_fill_f(float* __restrict__ o, int n, float v)
{
    int i = blockIdx.x * 256 + threadIdx.x;
    if (i < n) o[i] = v;
}

__global__ __launch_bounds__(256) void k_cvt_f2b(const float* __restrict__ in, bf16* __restrict__ o, int n)
{
    int i = blockIdx.x * 256 + threadIdx.x;
    if (i < n) o[i] = f2b(in[i]);
}

__global__ __launch_bounds__(256) void k_init_nodes(
    const float* __restrict__ x, const int* __restrict__ tidx, const int* __restrict__ bidx,
    const float* __restrict__ Wn, const float* __restrict__ bn,
    const float* __restrict__ embt, const float* __restrict__ embb,
    bf16* __restrict__ h, int N)
{
    int i = blockIdx.x * 256 + threadIdx.x;
    if (i >= N * HID) return;
    int node = i >> 6, c = i & 63;
    float acc = bn[c] + embt[tidx[node] * HID + c] + embb[bidx[node] * HID + c];
#pragma unroll
    for (int j = 0; j < 5; ++j)
        acc += x[node * 5 + j] * Wn[j * HID + c];
    h[i] = f2b(acc);
}

// Folded Q-weight [64][288] f32 + bias [288] per (lr), HEAD-INTERLEAVED columns:
//   col i*4+h     : A_h[j][i] = sum_c Wq[j,hc]*Wk[i,hc]
//   col 256+t*4+h : sum_c Wq[j,hc]*We[t,hc]
//   col 280+h     : sum_c Wq[j,hc]*(bk+be)[hc]
__global__ __launch_bounds__(256) void k_prep_q(
    const float* __restrict__ Wq, const float* __restrict__ bq,
    const float* __restrict__ Wk, const float* __restrict__ bk,
    const float* __restrict__ We, const float* __restrict__ be,
    float* __restrict__ WQeff, float* __restrict__ QBias)
{
    const int lr = blockIdx.x >> 2, h = blockIdx.x & 3;
    __shared__ float Ql[65 * 64];
    __shared__ float Rl[71 * 64];
    const float* Wq_ = Wq + (size_t)lr * HID * HC;
    const float* Wk_ = Wk + (size_t)lr * HID * HC;
    const float* We_ = We + (size_t)lr * EDIM * HC;
    const float* bq_ = bq + (size_t)lr * HC;
    const float* bk_ = bk + (size_t)lr * HC;
    const float* be_ = be + (size_t)lr * HC;
    for (int i = threadIdx.x; i < 65 * 64; i += 256) {
        int j = i >> 6, c = i & 63;
        Ql[i] = (j < 64) ? Wq_[j * HC + h * 64 + c] : bq_[h * 64 + c];
    }
    for (int i = threadIdx.x; i < 71 * 64; i += 256) {
        int r = i >> 6, c = i & 63;
        Rl[i] = (r < 64) ? Wk_[r * HC + h * 64 + c]
              : (r < 70) ? We_[(r - 64) * HC + h * 64 + c]
                         : (bk_[h * 64 + c] + be_[h * 64 + c]);
    }
    __syncthreads();
    for (int idx = threadIdx.x; idx < 65 * 71; idx += 256) {
        int j = idx / 71, col = idx % 71;
        float dot = 0.f;
#pragma unroll 8
        for (int c = 0; c < 64; ++c) dot += Ql[j * 64 + c] * Rl[col * 64 + c];
        int cm = (col < 64) ? (col * 4 + h) : (col < 70) ? (256 + (col - 64) * 4 + h) : (280 + h);
        if (j < 64) WQeff[((size_t)lr * 64 + j) * 288 + cm] = dot;
        else        QBias[(size_t)lr * 288 + cm] = dot;
    }
    for (int idx = threadIdx.x; idx < 64 * 4; idx += 256) {
        int j = idx >> 2, u = idx & 3;
        WQeff[((size_t)lr * 64 + j) * 288 + 284 + u] = 0.f;
    }
    if (threadIdx.x < 4) QBias[(size_t)lr * 288 + 284 + threadIdx.x] = 0.f;
}

// bveff head-interleaved: bveff[lr*256 + c*4+h] = bv[h*64+c] + be[h*64+c]
__global__ __launch_bounds__(256) void k_prep_vbias(
    const float* __restrict__ bv, const float* __restrict__ be, float* __restrict__ bveff)
{
    int i = blockIdx.x * 256 + threadIdx.x;   // 8 * 256
    int lr = i >> 8, idx = i & 255;
    int h = idx & 3, c = idx >> 2;
    bveff[i] = bv[lr * 256 + h * 64 + c] + be[lr * 256 + h * 64 + c];
}

// Pack f32 row-major [64][ld] -> bf16 MFMA B-frag; perm=1 maps phys col n -> src col (n&3)*64+(n>>2)
__global__ __launch_bounds__(256) void k_pack(
    const float* __restrict__ src, bf16* __restrict__ dst,
    int ld, int matStride, int fragStride, int perm)
{
    const int mat = blockIdx.y, tile = blockIdx.x;
    const float* S = src + (size_t)mat * matStride;
    bf16* D = dst + (size_t)mat * fragStride + tile * 1024;
    for (int idx = threadIdx.x; idx < 1024; idx += 256) {
        int ks = idx >> 9, r = idx & 511;
        int lane = r >> 3, j = r & 7;
        int k = ks * 32 + ((lane >> 4) << 3) + j;
        int n = tile * 16 + (lane & 15);
        int nsrc = perm ? ((n & 3) * 64 + (n >> 2)) : n;
        D[ks * 512 + r] = f2b(S[k * ld + nsrc]);
    }
}

// Unified MFMA GEMM: out[N, NTILES*16] = h[N,64] @ Wfrag + bias
// MODE 0: bf16 '='; 1: f32 '='; 2: f32 '+='
template<int NTILES, int MODE>
__global__ __launch_bounds__(256, 3) void k_gemm(
    const bf16* __restrict__ hin, const bf16* __restrict__ wfrag,
    const float* __restrict__ bias, void* __restrict__ outp, int N)
{
    __shared__ __align__(16) short wl[NTILES * 1024];
    __shared__ __align__(16) short hl[64 * 72];
    __shared__ float bl[NTILES * 16];
    {
        const uint4* wsrc = (const uint4*)wfrag;
        uint4* wdst = (uint4*)wl;
        for (int i = threadIdx.x; i < NTILES * 128; i += 256) wdst[i] = wsrc[i];
        for (int i = threadIdx.x; i < NTILES * 16; i += 256) bl[i] = bias[i];
    }
    const int lane = threadIdx.x & 63, wv = threadIdx.x >> 6;
    const int m = lane & 15, q = lane >> 4;
    const int ntile_tot = (N + 63) >> 6;
    const int ldo = NTILES * 16;
    for (int t = blockIdx.x; t < ntile_tot; t += gridDim.x) {
        const int row0 = t << 6;
        __syncthreads();
        {
            const uint4* hsrc = (const uint4*)(hin + (size_t)row0 * 64);
            for (int i = threadIdx.x; i < 512; i += 256) {
                int r = i >> 3, cc = i & 7;
                uint4 v = (row0 + r < N) ? hsrc[i] : make_uint4(0u, 0u, 0u, 0u);
                *(uint4*)&hl[r * 72 + cc * 8] = v;
            }
        }
        __syncthreads();
        short8 a0 = *(const short8*)&hl[(wv * 16 + m) * 72 + q * 8];
        short8 a1 = *(const short8*)&hl[(wv * 16 + m) * 72 + 32 + q * 8];
        for (int nt = 0; nt < NTILES; ++nt) {
            short8 b0 = *(const short8*)&wl[(nt * 2 + 0) * 512 + lane * 8];
            short8 b1 = *(const short8*)&wl[(nt * 2 + 1) * 512 + lane * 8];
            float4v acc = {0.f, 0.f, 0.f, 0.f};
            acc = __builtin_amdgcn_mfma_f32_16x16x32_bf16(a0, b0, acc, 0, 0, 0);
            acc = __builtin_amdgcn_mfma_f32_16x16x32_bf16(a1, b1, acc, 0, 0, 0);
            const float bb = bl[nt * 16 + m];
            const int colg = nt * 16 + m;
#pragma unroll
            for (int r = 0; r < 4; ++r) {
                int row = row0 + wv * 16 + q * 4 + r;
                if (row < N) {
                    float val = acc[r] + bb;
                    if (MODE == 0)      ((bf16*)outp)[(size_t)row * ldo + colg] = f2b(val);
                    else if (MODE == 1) ((float*)outp)[(size_t)row * ldo + colg] = val;
                    else                ((float*)outp)[(size_t)row * ldo + colg] += val;
                }
            }
        }
    }
}

// logits: 4 edges/wave, 16 lanes/edge. Q head-interleaved. Stores exp(l).
__global__ __launch_bounds__(256, 4) void k_elog(
    const int* __restrict__ src, const int* __restrict__ dst, const float* __restrict__ ea,
    const bf16* __restrict__ hsrc, const bf16* __restrict__ Q,
    float* __restrict__ expl, float* __restrict__ den, int nE, int lo, int hi)
{
    const int lane = threadIdx.x & 63;
    const int i16 = lane & 15, slot = lane >> 4;
    const int wv = (blockIdx.x << 2) + (threadIdx.x >> 6);
    const int step = gridDim.x << 2;
    for (int eb = wv; (eb << 2) < nE; eb += step) {
        const int e = (eb << 2) + slot;
        const bool act = (e < nE);
        const int d = act ? dst[e] : lo;
        const bool in = act && d >= lo && d < hi;
        const int s = in ? src[e] : 0;
        const bf16* qr = Q + (size_t)(d - lo) * 288;
        float p0 = 0.f, p1 = 0.f, p2 = 0.f, p3 = 0.f;
        if (in) {
            uint2 hv = *(const uint2*)(hsrc + (size_t)s * 64 + (i16 << 2));
            uint4 qa = *(const uint4*)(qr + (i16 << 4));
            uint4 qb = *(const uint4*)(qr + (i16 << 4) + 8);
            float x0 = blo(hv.x), x1 = bhi(hv.x), x2 = blo(hv.y), x3 = bhi(hv.y);
            p0 += x0 * blo(qa.x); p1 += x0 * bhi(qa.x); p2 += x0 * blo(qa.y); p3 += x0 * bhi(qa.y);
            p0 += x1 * blo(qa.z); p1 += x1 * bhi(qa.z); p2 += x1 * blo(qa.w); p3 += x1 * bhi(qa.w);
            p0 += x2 * blo(qb.x); p1 += x2 * bhi(qb.x); p2 += x2 * blo(qb.y); p3 += x2 * bhi(qb.y);
            p0 += x3 * blo(qb.z); p1 += x3 * bhi(qb.z); p2 += x3 * blo(qb.w); p3 += x3 * bhi(qb.w);
        }
#pragma unroll
        for (int m = 1; m <= 8; m <<= 1) {
            p0 += __shfl_xor(p0, m);
            p1 += __shfl_xor(p1, m);
            p2 += __shfl_xor(p2, m);
            p3 += __shfl_xor(p3, m);
        }
        if (in && i16 == 0) {
            float ev[EDIM];
#pragma unroll
            for (int t = 0; t < EDIM; ++t) ev[t] = ea[(size_t)e * 6 + t];
            float pl[4] = {p0, p1, p2, p3};
#pragma unroll
            for (int h = 0; h < 4; ++h) {
                float l = pl[h] + b2f(qr[280 + h]);
#pragma unroll
                for (int t = 0; t < EDIM; ++t) l += ev[t] * b2f(qr[256 + t * 4 + h]);
                float ex = __expf(l * 0.125f);
                expl[(size_t)e * 4 + h] = ex;
                atomicAdd(&den[(size_t)d * 4 + h], ex);
            }
        }
    }
}

// accum: 2 edges/wave, V head-interleaved. g[d,c] += sum_h al_h*(V[s]_{c,h} + (We^T ea)_{h,c})
__global__ __launch_bounds__(256, 4) void k_eacc(
    const int* __restrict__ src, const int* __restrict__ dst, const float* __restrict__ ea,
    const bf16* __restrict__ V, const float* __restrict__ Wer,
    const float* __restrict__ expl, const float* __restrict__ den,
    float* __restrict__ g, int nE, int lo, int hi)
{
    __shared__ float Wes[EDIM * HC];
    for (int i = threadIdx.x; i < EDIM * HC; i += 256) Wes[i] = Wer[i];
    __syncthreads();
    const int lane = threadIdx.x & 63;
    const int wv = (blockIdx.x << 2) + (threadIdx.x >> 6);
    const int step = gridDim.x << 2;
    for (int eb = wv; (eb << 1) < nE; eb += step) {
#pragma unroll
        for (int u = 0; u < 2; ++u) {
            const int e = (eb << 1) + u;
            if (e >= nE) break;
            const int s = src[e];
            if (s < lo || s >= hi) continue;
            const int d = dst[e];
            uint2 vv = *(const uint2*)(V + (size_t)(s - lo) * 256 + (lane << 2));
            float v0 = blo(vv.x), v1 = bhi(vv.x), v2 = blo(vv.y), v3 = bhi(vv.y);
            float al[4];
#pragma unroll
            for (int h = 0; h < 4; ++h)
                al[h] = expl[(size_t)e * 4 + h] * 0.25f / den[(size_t)d * 4 + h];
            float ev[EDIM];
#pragma unroll
            for (int t = 0; t < EDIM; ++t) ev[t] = ea[(size_t)e * 6 + t];
            float vh[4] = {v0, v1, v2, v3};
            float acc = 0.f;
#pragma unroll
            for (int h = 0; h < 4; ++h) {
                float val = vh[h];
#pragma unroll
                for (int t = 0; t < EDIM; ++t) val += ev[t] * Wes[t * HC + h * 64 + lane];
                acc += al[h] * val;
            }
            atomicAdd(&g[(size_t)d * 64 + lane], acc);
        }
    }
}

__global__ __launch_bounds__(256) void k_relu_g2h(const float* __restrict__ g, bf16* __restrict__ h, int n)
{
    int i = blockIdx.x * 256 + threadIdx.x;
    if (i < n) h[i] = f2b(fmaxf(g[i], 0.f));
}

__global__ __launch_bounds__(256) void k_relu_bf(bf16* __restrict__ h, int n)
{
    int i = blockIdx.x * 256 + threadIdx.x;
    if (i < n) { float x = b2f(h[i]); h[i] = f2b(x > 0.f ? x : 0.f); }
}

extern "C" void kernel_launch(void* const* d_in, const int* in_sizes, int n_in,
                              void* d_out, int out_size, void* d_ws, size_t ws_size,
                              hipStream_t stream)
{
    const float* x_start = (const float*)d_in[0];
    const float* x_end   = (const float*)d_in[1];
    const int* start_type_idx = (const int*)d_in[2];
    const int* start_body_idx = (const int*)d_in[3];
    const int* end_type_idx   = (const int*)d_in[4];
    const int* end_body_idx   = (const int*)d_in[5];
    const int* src_ps = (const int*)d_in[6];
    const int* dst_ps = (const int*)d_in[7];
    const int* src_se = (const int*)d_in[8];
    const int* dst_se = (const int*)d_in[9];
    const int* src_es = (const int*)d_in[10];
    const int* dst_es = (const int*)d_in[11];
    const int* src_tp = (const int*)d_in[12];
    const int* dst_tp = (const int*)d_in[13];
    const float* ea_ps = (const float*)d_in[14];
    const float* ea_se = (const float*)d_in[15];
    const float* ea_es = (const float*)d_in[16];
    const float* ea_tp = (const float*)d_in[17];
    const float* emb_start_type = (const float*)d_in[18];
    const float* emb_start_body = (const float*)d_in[19];
    const float* emb_end_type   = (const float*)d_in[20];
    const float* emb_end_body   = (const float*)d_in[21];
    const float* emb_player = (const float*)d_in[22];
    const float* emb_team   = (const float*)d_in[23];
    const float* W_start = (const float*)d_in[24];
    const float* b_start = (const float*)d_in[25];
    const float* W_end   = (const float*)d_in[26];
    const float* b_end   = (const float*)d_in[27];
    const float* Wq = (const float*)d_in[28];
    const float* bq = (const float*)d_in[29];
    const float* Wk = (const float*)d_in[30];
    const float* bk = (const float*)d_in[31];
    const float* Wv = (const float*)d_in[32];
    const float* bv = (const float*)d_in[33];
    const float* We = (const float*)d_in[34];
    const float* be = (const float*)d_in[35];
    const float* Wskip = (const float*)d_in[36];
    const float* bskip = (const float*)d_in[37];
    const float* W_head = (const float*)d_in[38];
    const float* b_head = (const float*)d_in[39];

    // ---- workspace carve (~226.6 MB of 256 MB) ----
    size_t off = 0;
    char* base = (char*)d_ws;
    auto carve = [&](size_t bytes) -> char* {
        char* q = base + off; off += (bytes + 255) & ~(size_t)255; return q;
    };
    bf16* h0 = (bf16*)carve((size_t)NS * HID * 2);
    bf16* h1 = (bf16*)carve((size_t)NEN * HID * 2);
    bf16* h2 = (bf16*)carve((size_t)NPL * HID * 2);
    bf16* h3 = (bf16*)carve((size_t)NT * HID * 2);
    float* g0 = (float*)carve((size_t)NS * HID * 4);
    float* g1 = (float*)carve((size_t)NEN * HID * 4);
    float* g2 = (float*)carve((size_t)NPL * HID * 4);
    bf16* QV  = (bf16*)carve((size_t)CH * 288 * 2);
    float* expl = (float*)carve((size_t)EE * 4 * 4);
    float* den = (float*)carve((size_t)200000 * 4 * 4);
    float* WQeff = (float*)carve((size_t)8 * 64 * 288 * 4);
    float* QBias = (float*)carve((size_t)8 * 288 * 4);
    float* bveff = (float*)carve((size_t)8 * 256 * 4);
    bf16* Qfrag = (bf16*)carve((size_t)8 * 18 * 1024 * 2);
    bf16* Vfrag = (bf16*)carve((size_t)8 * 16 * 1024 * 2);
    bf16* SKfrag = (bf16*)carve((size_t)8 * 4 * 1024 * 2);
    bf16* HDfrag = (bf16*)carve((size_t)2 * 1024 * 2);
    const size_t req = off;

    if (ws_size < req) {
        k_fill_f<<<(out_size + 255) / 256, 256, 0, stream>>>((float*)d_out, out_size, (float)(ws_size >> 20));
        return;
    }

    // ---- weight prep + frag packing ----
    k_prep_q<<<32, 256, 0, stream>>>(Wq, bq, Wk, bk, We, be, WQeff, QBias);
    k_prep_vbias<<<8, 256, 0, stream>>>(bv, be, bveff);
    k_pack<<<dim3(18, 8), 256, 0, stream>>>(WQeff, Qfrag, 288, 64 * 288, 18 * 1024, 0);
    k_pack<<<dim3(16, 8), 256, 0, stream>>>(Wv, Vfrag, 256, HID * HC, 16 * 1024, 1);
    k_pack<<<dim3(4, 8), 256, 0, stream>>>(Wskip, SKfrag, 64, HID * HID, 4 * 1024, 0);
    k_pack<<<dim3(2, 1), 256, 0, stream>>>(W_head, HDfrag, 32, 0, 2 * 1024, 0);

    // ---- initial node features ----
    k_init_nodes<<<(NS * HID + 255) / 256, 256, 0, stream>>>(
        x_start, start_type_idx, start_body_idx, W_start, b_start,
        emb_start_type, emb_start_body, h0, NS);
    k_init_nodes<<<(NEN * HID + 255) / 256, 256, 0, stream>>>(
        x_end, end_type_idx, end_body_idx, W_end, b_end,
        emb_end_type, emb_end_body, h1, NEN);
    k_cvt_f2b<<<(NPL * HID + 255) / 256, 256, 0, stream>>>(emb_player, h2, NPL * HID);
    k_cvt_f2b<<<(NT * HID + 255) / 256, 256, 0, stream>>>(emb_team, h3, NT * HID);

    struct RelDesc {
        int srcN, dstN, nE;
        const int *src, *dst;
        const float* ea;
        bf16 *hsrc, *hdst;
        float* gdst;
    };

    auto gemmGrid = [](int N) { int g = (N + 63) / 64; return g > 2048 ? 2048 : g; };

    for (int l = 0; l < 2; ++l) {
        RelDesc rels[4] = {
            { NPL, NS,  EE,   src_ps, dst_ps, ea_ps, h2, h0, g0 },
            { NS,  NEN, EE,   src_se, dst_se, ea_se, h0, h1, g1 },
            { NEN, NS,  EE,   src_es, dst_es, ea_es, h1, h0, g0 },
            { NT,  NPL, ETPE, src_tp, dst_tp, ea_tp, h3, h2, g2 },
        };
        for (int r = 0; r < 4; ++r) {
            const RelDesc& R = rels[r];
            const int wi = l * 4 + r;
            int gE4 = (R.nE + 15) / 16; if (gE4 > 2048) gE4 = 2048;
            int gE2 = (R.nE + 7) / 8;   if (gE2 > 2048) gE2 = 2048;

            // skip term: '=' initializes g (first writer per dst type), '+=' for second
            if (r == 2)
                k_gemm<4, 2><<<gemmGrid(R.dstN), 256, 0, stream>>>(
                    R.hdst, SKfrag + (size_t)wi * 4096, bskip + (size_t)wi * HID, R.gdst, R.dstN);
            else
                k_gemm<4, 1><<<gemmGrid(R.dstN), 256, 0, stream>>>(
                    R.hdst, SKfrag + (size_t)wi * 4096, bskip + (size_t)wi * HID, R.gdst, R.dstN);

            hipMemsetAsync(den, 0, (size_t)R.dstN * 4 * 4, stream);
            for (int c0 = 0; c0 < R.dstN; c0 += CH) {
                int cnt = (R.dstN - c0 < CH) ? (R.dstN - c0) : CH;
                k_gemm<18, 0><<<gemmGrid(cnt), 256, 0, stream>>>(
                    R.hdst + (size_t)c0 * 64, Qfrag + (size_t)wi * 18432,
                    QBias + (size_t)wi * 288, QV, cnt);
                k_elog<<<gE4, 256, 0, stream>>>(R.src, R.dst, R.ea, R.hsrc, QV,
                                                expl, den, R.nE, c0, c0 + cnt);
            }
            for (int c0 = 0; c0 < R.srcN; c0 += CH) {
                int cnt = (R.srcN - c0 < CH) ? (R.srcN - c0) : CH;
                k_gemm<16, 0><<<gemmGrid(cnt), 256, 0, stream>>>(
                    R.hsrc + (size_t)c0 * 64, Vfrag + (size_t)wi * 16384,
                    bveff + (size_t)wi * 256, QV, cnt);
                k_eacc<<<gE2, 256, 0, stream>>>(R.src, R.dst, R.ea, QV,
                                                We + (size_t)wi * EDIM * HC,
                                                expl, den, R.gdst, R.nE, c0, c0 + cnt);
            }
        }
        k_relu_g2h<<<(NS * HID + 255) / 256, 256, 0, stream>>>(g0, h0, NS * HID);
        k_relu_g2h<<<(NEN * HID + 255) / 256, 256, 0, stream>>>(g1, h1, NEN * HID);
        k_relu_g2h<<<(NPL * HID + 255) / 256, 256, 0, stream>>>(g2, h2, NPL * HID);
        k_relu_bf<<<(NT * HID + 255) / 256, 256, 0, stream>>>(h3, NT * HID);
    }

    k_gemm<2, 1><<<2048, 256, 0, stream>>>(h1, HDfrag, b_head, d_out, NEN);
}